// Round 1
// baseline (431.263 us; speedup 1.0000x reference)
//
#include <hip/hip_runtime.h>
#include <math.h>

#define B 4
#define P 19248
#define C 81
#define M 32
#define K1 100
#define K2 15
#define G 32
#define HP 138
#define HO 550
#define FEPS 1e-6f
#define NLOC 19   // ceil(P/1024)

// ---------------- Stage 1: conf1 = softmax(conf, axis=2)[:, :, 1] ----------
// one wave (64 lanes) per row of 81 classes
__global__ void k_conf1(const float* __restrict__ conf, float* __restrict__ conf1) {
    int gid  = blockIdx.x * blockDim.x + threadIdx.x;
    int wave = gid >> 6;
    int lane = threadIdx.x & 63;
    if (wave >= B * P) return;
    const float* row = conf + (size_t)wave * C;
    float x0 = (lane < C)      ? row[lane]      : -INFINITY;
    float x1 = (lane + 64 < C) ? row[lane + 64] : -INFINITY;
    float m = fmaxf(x0, x1);
#pragma unroll
    for (int o = 32; o; o >>= 1) m = fmaxf(m, __shfl_xor(m, o, 64));
    float s = 0.f;
    if (lane < C)      s += expf(x0 - m);
    if (lane + 64 < C) s += expf(x1 - m);
#pragma unroll
    for (int o = 32; o; o >>= 1) s += __shfl_xor(s, o, 64);
    if (lane == 0) conf1[wave] = expf(row[1] - m) / s;
}

// ---------------- Stage 2: top-100 by conf1 (stable, desc) + gather --------
// one block of 1024 threads per batch; values held in registers
__global__ __launch_bounds__(1024) void k_top100(
    const float* __restrict__ conf1, const float* __restrict__ loc,
    const float* __restrict__ mask,  int* __restrict__ order,
    float* __restrict__ sconf, float* __restrict__ sloc,
    float* __restrict__ smask) {
    int b = blockIdx.x;
    int tid = threadIdx.x;
    int lane = tid & 63;
    int wid = tid >> 6;     // 0..15
    const float* c1 = conf1 + (size_t)b * P;

    float lv[NLOC];
#pragma unroll
    for (int s = 0; s < NLOC; ++s) {
        int p = tid + s * 1024;
        lv[s] = (p < P) ? c1[p] : -INFINITY;
    }

    __shared__ float s_wv[16];
    __shared__ int   s_wi[16];
    __shared__ int   s_bi;
    __shared__ int   s_order[K1];
    __shared__ float s_conf[K1];

    for (int k = 0; k < K1; ++k) {
        float bv = -INFINITY;
        int bslot = -1;
#pragma unroll
        for (int s = 0; s < NLOC; ++s)
            if (lv[s] > bv) { bv = lv[s]; bslot = s; }
        int bi = (bslot >= 0) ? (tid + bslot * 1024) : (1 << 30);
#pragma unroll
        for (int o = 32; o; o >>= 1) {
            float ov = __shfl_xor(bv, o, 64);
            int   oi = __shfl_xor(bi, o, 64);
            if (ov > bv || (ov == bv && oi < bi)) { bv = ov; bi = oi; }
        }
        if (lane == 0) { s_wv[wid] = bv; s_wi[wid] = bi; }
        __syncthreads();
        if (tid == 0) {
            float xv = s_wv[0]; int xi = s_wi[0];
            for (int w = 1; w < 16; ++w)
                if (s_wv[w] > xv || (s_wv[w] == xv && s_wi[w] < xi)) { xv = s_wv[w]; xi = s_wi[w]; }
            s_bi = xi; s_order[k] = xi; s_conf[k] = xv;
        }
        __syncthreads();
        int win = s_bi;
        if ((win & 1023) == tid) {
            int slot = win >> 10;
#pragma unroll
            for (int s = 0; s < NLOC; ++s)
                if (s == slot) lv[s] = -INFINITY;
        }
    }
    __syncthreads();
    for (int t = tid; t < K1; t += 1024) {
        order[b * K1 + t] = s_order[t];
        sconf[b * K1 + t] = s_conf[t];
    }
    for (int t = tid; t < K1 * 4; t += 1024) {
        int k = t >> 2, d = t & 3;
        sloc[(b * K1 + k) * 4 + d] = loc[((size_t)b * P + s_order[k]) * 4 + d];
    }
    for (int t = tid; t < K1 * M; t += 1024) {
        int k = t >> 5, d = t & 31;
        smask[(b * K1 + k) * M + d] = mask[((size_t)b * P + s_order[k]) * M + d];
    }
}

// ---------------- Stage 3: 32x32 gaussians for the 100 boxes ---------------
__global__ void k_gauss(const float* __restrict__ sloc, float* __restrict__ gauss) {
    int bk = blockIdx.x;                    // b*K1 + k
    const float* l = sloc + bk * 4;
    float cx = l[0], cy = l[1];
    float sx = fabsf(l[2]) * 0.5f + 0.001f;
    float sy = fabsf(l[3]) * 0.5f + 0.001f;
    float dsx = 2.f * sx * sx;
    float dsy = 2.f * sy * sy;
    for (int p = threadIdx.x; p < G * G; p += 256) {
        int y = p >> 5, x = p & 31;
        float xs = (x + 0.5f) / (float)G;
        float ys = (y + 0.5f) / (float)G;
        float dx2 = (xs - cx) * (xs - cx) / dsx;
        float dy2 = (ys - cy) * (ys - cy) / dsy;
        gauss[(size_t)bk * (G * G) + p] = expf(-(dy2 + dx2));
    }
}

// ---------------- Stage 4: pairwise gauss IoU, iou_max per column ----------
// one wave per (b,i,j); iou symmetric -> only i<j; atomicMax on uint bits
__global__ void k_iou(const float* __restrict__ gauss, unsigned int* __restrict__ ioumax) {
    int gid  = blockIdx.x * blockDim.x + threadIdx.x;
    int wave = gid >> 6;
    int lane = threadIdx.x & 63;
    if (wave >= B * K1 * K1) return;
    int b = wave / (K1 * K1);
    int rem = wave - b * K1 * K1;
    int i = rem / K1, j = rem % K1;
    if (i >= j) return;
    const float* gi = gauss + ((size_t)b * K1 + i) * (G * G);
    const float* gj = gauss + ((size_t)b * K1 + j) * (G * G);
    float inter = 0.f, uni = 0.f;
#pragma unroll
    for (int p = lane; p < G * G; p += 64) {
        float a = gi[p], c = gj[p];
        inter += fminf(a, c);
        uni   += fmaxf(a, c);
    }
#pragma unroll
    for (int o = 32; o; o >>= 1) {
        inter += __shfl_xor(inter, o, 64);
        uni   += __shfl_xor(uni,   o, 64);
    }
    if (lane == 0) {
        float iou = inter / uni;              // both > 0
        atomicMax(&ioumax[b * K1 + j], __float_as_uint(iou));
    }
}

// ---------------- Stage 5: keep = 15 smallest iou_max (stable) + gather ----
__global__ void k_keep(const unsigned int* __restrict__ ioumax,
                       const float* __restrict__ sloc, const float* __restrict__ smask,
                       const float* __restrict__ sconf,
                       float* __restrict__ kloc, float* __restrict__ kmask,
                       float* __restrict__ kconf) {
    int b = blockIdx.x;
    int lane = threadIdx.x;  // 64 threads
    float v0 = (lane < K1)      ? __uint_as_float(ioumax[b * K1 + lane])      : INFINITY;
    float v1 = (lane + 64 < K1) ? __uint_as_float(ioumax[b * K1 + lane + 64]) : INFINITY;
    __shared__ int s_keep[K2];
    for (int k = 0; k < K2; ++k) {
        float bv; int bi;
        if (v0 <= v1) { bv = v0; bi = lane; }        // tie -> smaller index
        else          { bv = v1; bi = lane + 64; }
#pragma unroll
        for (int o = 32; o; o >>= 1) {
            float ov = __shfl_xor(bv, o, 64);
            int   oi = __shfl_xor(bi, o, 64);
            if (ov < bv || (ov == bv && oi < bi)) { bv = ov; bi = oi; }
        }
        if (bi == lane)           v0 = INFINITY;
        else if (bi == lane + 64) v1 = INFINITY;
        if (lane == 0) s_keep[k] = bi;
    }
    __syncthreads();
    for (int t = lane; t < K2 * M; t += 64) {
        int k = t >> 5, d = t & 31;
        kmask[(b * K2 + k) * M + d] = smask[(b * K1 + s_keep[k]) * M + d];
    }
    for (int t = lane; t < K2 * 4; t += 64) {
        int k = t >> 2, d = t & 3;
        kloc[(b * K2 + k) * 4 + d] = sloc[(b * K1 + s_keep[k]) * 4 + d];
    }
    if (lane < K2) kconf[b * K2 + lane] = sconf[b * K1 + s_keep[lane]];
}

// ---------------- Stage 6: final_conf at 138x138 ---------------------------
__global__ void k_fconf(const float* __restrict__ proto, const float* __restrict__ kloc,
                        const float* __restrict__ kmask, const float* __restrict__ kconf,
                        float* __restrict__ fconf) {
    int b = blockIdx.y;
    int p = blockIdx.x * 256 + threadIdx.x;
    __shared__ float s_km[K2][M];
    __shared__ float s_loc[K2][4];
    __shared__ float s_cf[K2];
    for (int t = threadIdx.x; t < K2 * M; t += 256) s_km[t >> 5][t & 31] = kmask[b * K2 * M + t];
    for (int t = threadIdx.x; t < K2 * 4; t += 256) s_loc[t >> 2][t & 3] = kloc[b * K2 * 4 + t];
    if (threadIdx.x < K2) s_cf[threadIdx.x] = kconf[b * K2 + threadIdx.x];
    __syncthreads();
    if (p >= HP * HP) return;
    int h = p / HP, w = p % HP;
    const float* pr = proto + (((size_t)b * HP + h) * HP + w) * M;
    float pv[M];
#pragma unroll
    for (int m = 0; m < M; ++m) pv[m] = pr[m];
    float ys = (h + 0.5f) / (float)HP;
    float xs = (w + 0.5f) / (float)HP;
    float sum_a = 0.f, sum_a2 = 0.f;
#pragma unroll 1
    for (int k = 0; k < K2; ++k) {
        float d = 0.f;
#pragma unroll
        for (int m = 0; m < M; ++m) d += pv[m] * s_km[k][m];
        float sig = 1.f / (1.f + expf(-d));
        float cx = s_loc[k][0], cy = s_loc[k][1];
        float sx = fabsf(s_loc[k][2]) * 0.5f + 0.001f;
        float sy = fabsf(s_loc[k][3]) * 0.5f + 0.001f;
        float dx2 = (xs - cx) * (xs - cx) / (2.f * sx * sx);
        float dy2 = (ys - cy) * (ys - cy) / (2.f * sy * sy);
        float ug = expf(-(dy2 + dx2));
        float a = sig * ug * s_cf[k];
        sum_a  += a;
        sum_a2 += a * a;
    }
    float fin = 1.f - sum_a2 / (sum_a + FEPS);
    if (!(fin == fin)) fin = 0.f;
    fconf[(size_t)b * HP * HP + p] = fin;
}

// ---------------- Stage 7: bilinear resize 138->550 fused with variance ----
__global__ void k_reduce(const float* __restrict__ fconf, const float* __restrict__ original,
                         float* __restrict__ acc) {
    int idx = blockIdx.x * 256 + threadIdx.x;
    float contrib = 0.f;
    if (idx < HO * HO) {
        int y = idx / HO, x = idx % HO;
        const float scale = (float)HP / (float)HO;
        float fy = (y + 0.5f) * scale - 0.5f;
        float fx = (x + 0.5f) * scale - 0.5f;
        float y0f = floorf(fy), x0f = floorf(fx);
        float wy = fy - y0f, wx = fx - x0f;
        int y0 = (int)y0f, x0 = (int)x0f;
        int iy0 = max(y0, 0), iy1 = min(y0 + 1, HP - 1);
        int ix0 = max(x0, 0), ix1 = min(x0 + 1, HP - 1);
        float r[B];
#pragma unroll
        for (int b = 0; b < B; ++b) {
            const float* F = fconf + (size_t)b * HP * HP;
            float v00 = F[iy0 * HP + ix0], v01 = F[iy0 * HP + ix1];
            float v10 = F[iy1 * HP + ix0], v11 = F[iy1 * HP + ix1];
            r[b] = (1.f - wy) * ((1.f - wx) * v00 + wx * v01)
                 +        wy  * ((1.f - wx) * v10 + wx * v11);
        }
        float t = r[0] + r[1] + r[2] + r[3];
        float s = 0.f;
#pragma unroll
        for (int c = 0; c < 3; ++c) {
            float o[B], wm = 0.f;
#pragma unroll
            for (int b = 0; b < B; ++b) {
                o[b] = original[(((size_t)b * 3 + c) * HO + y) * HO + x];
                wm += o[b] * r[b];
            }
#pragma unroll
            for (int b = 0; b < B; ++b) {
                float d = o[b] - wm;
                s += d * d * r[b];
            }
        }
        contrib = s / (t + FEPS);
    }
    __shared__ float red[256];
    red[threadIdx.x] = contrib;
    __syncthreads();
    for (int off = 128; off; off >>= 1) {
        if (threadIdx.x < off) red[threadIdx.x] += red[threadIdx.x + off];
        __syncthreads();
    }
    if (threadIdx.x == 0) atomicAdd(acc, red[0]);
}

__global__ void k_final(const float* __restrict__ acc, float* __restrict__ out) {
    out[0] = acc[0] / 100.f;
}

extern "C" void kernel_launch(void* const* d_in, const int* in_sizes, int n_in,
                              void* d_out, int out_size, void* d_ws, size_t ws_size,
                              hipStream_t stream) {
    (void)in_sizes; (void)n_in; (void)out_size; (void)ws_size;
    const float* original = (const float*)d_in[0];
    const float* loc      = (const float*)d_in[1];
    const float* conf     = (const float*)d_in[2];
    const float* mask     = (const float*)d_in[3];
    const float* proto    = (const float*)d_in[4];

    char* ws = (char*)d_ws;
    size_t off = 0;
    auto alloc = [&](size_t bytes) -> void* {
        void* p = ws + off;
        off += (bytes + 255) & ~(size_t)255;
        return p;
    };
    float* conf1        = (float*)alloc((size_t)B * P * sizeof(float));
    int*   order        = (int*)  alloc((size_t)B * K1 * sizeof(int));
    float* sconf        = (float*)alloc((size_t)B * K1 * sizeof(float));
    float* sloc         = (float*)alloc((size_t)B * K1 * 4 * sizeof(float));
    float* smask        = (float*)alloc((size_t)B * K1 * M * sizeof(float));
    float* gauss        = (float*)alloc((size_t)B * K1 * G * G * sizeof(float));
    unsigned int* iomax = (unsigned int*)alloc((size_t)B * K1 * sizeof(unsigned int));
    float* kloc         = (float*)alloc((size_t)B * K2 * 4 * sizeof(float));
    float* kmask        = (float*)alloc((size_t)B * K2 * M * sizeof(float));
    float* kconf        = (float*)alloc((size_t)B * K2 * sizeof(float));
    float* fconf        = (float*)alloc((size_t)B * HP * HP * sizeof(float));
    float* acc          = (float*)alloc(sizeof(float));

    hipMemsetAsync(iomax, 0, (size_t)B * K1 * sizeof(unsigned int), stream);
    hipMemsetAsync(acc, 0, sizeof(float), stream);

    // Stage 1: 76992 waves
    k_conf1<<<(B * P) / 4, 256, 0, stream>>>(conf, conf1);
    // Stage 2: one 1024-block per batch
    k_top100<<<B, 1024, 0, stream>>>(conf1, loc, mask, order, sconf, sloc, smask);
    // Stage 3
    k_gauss<<<B * K1, 256, 0, stream>>>(sloc, gauss);
    // Stage 4: one wave per (b,i,j)
    k_iou<<<(B * K1 * K1 * 64 + 255) / 256, 256, 0, stream>>>(gauss, iomax);
    // Stage 5
    k_keep<<<B, 64, 0, stream>>>(iomax, sloc, smask, sconf, kloc, kmask, kconf);
    // Stage 6
    dim3 g6((HP * HP + 255) / 256, B);
    k_fconf<<<g6, 256, 0, stream>>>(proto, kloc, kmask, kconf, fconf);
    // Stage 7
    k_reduce<<<(HO * HO + 255) / 256, 256, 0, stream>>>(fconf, original, acc);
    k_final<<<1, 1, 0, stream>>>(acc, (float*)d_out);
}

// Round 2
// 209.263 us; speedup vs baseline: 2.0609x; 2.0609x over previous
//
#include <hip/hip_runtime.h>
#include <math.h>

#define B 4
#define P 19248
#define C 81
#define M 32
#define K1 100
#define K2 15
#define G 32
#define HP 138
#define HO 550
#define FEPS 1e-6f
#define NLOC 19   // ceil(P/1024)

#define NBUCKET 8192   // bits >> 17; conf1 in (0,1) -> bucket < 8128
#define CAP 2048       // candidate cap (threshold-bucket overshoot is tiny)

// ---------------- Stage 1: conf1 = softmax(conf, axis=2)[:, :, 1] ----------
// one wave (64 lanes) per row of 81 classes
__global__ void k_conf1(const float* __restrict__ conf, float* __restrict__ conf1) {
    int gid  = blockIdx.x * blockDim.x + threadIdx.x;
    int wave = gid >> 6;
    int lane = threadIdx.x & 63;
    if (wave >= B * P) return;
    const float* row = conf + (size_t)wave * C;
    float x0 = (lane < C)      ? row[lane]      : -INFINITY;
    float x1 = (lane + 64 < C) ? row[lane + 64] : -INFINITY;
    float m = fmaxf(x0, x1);
#pragma unroll
    for (int o = 32; o; o >>= 1) m = fmaxf(m, __shfl_xor(m, o, 64));
    float s = 0.f;
    if (lane < C)      s += expf(x0 - m);
    if (lane + 64 < C) s += expf(x1 - m);
#pragma unroll
    for (int o = 32; o; o >>= 1) s += __shfl_xor(s, o, 64);
    if (lane == 0) conf1[wave] = expf(row[1] - m) / s;
}

// ---------------- Stage 2: top-100 by conf1 via radix-histogram select -----
// one block of 1024 threads per batch
__global__ __launch_bounds__(1024) void k_top100(
    const float* __restrict__ conf1, const float* __restrict__ loc,
    const float* __restrict__ mask,  int* __restrict__ order,
    float* __restrict__ sconf, float* __restrict__ sloc,
    float* __restrict__ smask) {
    int b = blockIdx.x;
    int tid = threadIdx.x;
    const float* c1 = conf1 + (size_t)b * P;

    __shared__ unsigned int hist[NBUCKET];
    __shared__ unsigned int gsum[1024];     // 8 buckets each
    __shared__ unsigned int g2[64];         // 16 groups each (128 buckets)
    __shared__ unsigned long long keys[CAP];
    __shared__ int s_T;
    __shared__ int s_cnt;
    __shared__ int   s_order[K1];
    __shared__ float s_conf[K1];

    for (int i = tid; i < NBUCKET; i += 1024) hist[i] = 0;
    if (tid == 0) s_cnt = 0;
    __syncthreads();

    // pass 1: histogram of float bit patterns (monotone for positive floats)
    unsigned int mybits[NLOC];
#pragma unroll
    for (int s = 0; s < NLOC; ++s) {
        int p = tid + s * 1024;
        mybits[s] = (p < P) ? __float_as_uint(c1[p]) : 0u;
        if (p < P) atomicAdd(&hist[mybits[s] >> 17], 1u);
    }
    __syncthreads();

    // hierarchical sums
    {
        unsigned int gs = 0;
#pragma unroll
        for (int i = 0; i < 8; ++i) gs += hist[tid * 8 + i];
        gsum[tid] = gs;
    }
    __syncthreads();
    if (tid < 64) {
        unsigned int gs = 0;
#pragma unroll
        for (int i = 0; i < 16; ++i) gs += gsum[tid * 16 + i];
        g2[tid] = gs;
    }
    __syncthreads();

    // threshold: smallest bucket T with suffix-count >= K1
    if (tid == 0) {
        int cum = 0;
        int S = 63;
        for (; S > 0; --S) {
            if (cum + (int)g2[S] >= K1) break;
            cum += (int)g2[S];
        }
        int gI = S * 16 + 15;
        for (; gI > S * 16; --gI) {
            if (cum + (int)gsum[gI] >= K1) break;
            cum += (int)gsum[gI];
        }
        int T = gI * 8 + 7;
        for (; T > gI * 8; --T) {
            cum += (int)hist[T];
            if (cum >= K1) break;
        }
        s_T = T;
    }
    __syncthreads();

    // pass 2: compact candidates (bucket >= T) as packed keys
    int T = s_T;
#pragma unroll
    for (int s = 0; s < NLOC; ++s) {
        int p = tid + s * 1024;
        if (p < P && (int)(mybits[s] >> 17) >= T) {
            int pos = atomicAdd(&s_cnt, 1);
            if (pos < CAP)
                keys[pos] = ((unsigned long long)mybits[s] << 32)
                          | (unsigned int)(0xFFFFFFFFu - (unsigned int)p);
        }
    }
    __syncthreads();
    int nc = min(s_cnt, CAP);

    // exact rank by counting strictly-greater keys (keys unique)
    if (tid < nc) {
        unsigned long long mk = keys[tid];
        int rank = 0;
        for (int i = 0; i < nc; ++i) rank += (keys[i] > mk);
        if (rank < K1) {
            unsigned int bits = (unsigned int)(mk >> 32);
            int idx = (int)(0xFFFFFFFFu - (unsigned int)(mk & 0xFFFFFFFFu));
            s_order[rank] = idx;
            s_conf[rank] = __uint_as_float(bits);
        }
    }
    __syncthreads();

    for (int t = tid; t < K1; t += 1024) {
        order[b * K1 + t] = s_order[t];
        sconf[b * K1 + t] = s_conf[t];
    }
    for (int t = tid; t < K1 * 4; t += 1024) {
        int k = t >> 2, d = t & 3;
        sloc[(b * K1 + k) * 4 + d] = loc[((size_t)b * P + s_order[k]) * 4 + d];
    }
    for (int t = tid; t < K1 * M; t += 1024) {
        int k = t >> 5, d = t & 31;
        smask[(b * K1 + k) * M + d] = mask[((size_t)b * P + s_order[k]) * M + d];
    }
}

// ---------------- Stage 3: 32x32 gaussians for the 100 boxes ---------------
__global__ void k_gauss(const float* __restrict__ sloc, float* __restrict__ gauss) {
    int bk = blockIdx.x;                    // b*K1 + k
    const float* l = sloc + bk * 4;
    float cx = l[0], cy = l[1];
    float sx = fabsf(l[2]) * 0.5f + 0.001f;
    float sy = fabsf(l[3]) * 0.5f + 0.001f;
    float dsx = 2.f * sx * sx;
    float dsy = 2.f * sy * sy;
    for (int p = threadIdx.x; p < G * G; p += 256) {
        int y = p >> 5, x = p & 31;
        float xs = (x + 0.5f) / (float)G;
        float ys = (y + 0.5f) / (float)G;
        float dx2 = (xs - cx) * (xs - cx) / dsx;
        float dy2 = (ys - cy) * (ys - cy) / dsy;
        gauss[(size_t)bk * (G * G) + p] = expf(-(dy2 + dx2));
    }
}

// ---------------- Stage 4: pairwise gauss IoU, iou_max per column ----------
// one wave per (b,i,j); iou symmetric -> only i<j; atomicMax on uint bits
__global__ void k_iou(const float* __restrict__ gauss, unsigned int* __restrict__ ioumax) {
    int gid  = blockIdx.x * blockDim.x + threadIdx.x;
    int wave = gid >> 6;
    int lane = threadIdx.x & 63;
    if (wave >= B * K1 * K1) return;
    int b = wave / (K1 * K1);
    int rem = wave - b * K1 * K1;
    int i = rem / K1, j = rem % K1;
    if (i >= j) return;
    const float* gi = gauss + ((size_t)b * K1 + i) * (G * G);
    const float* gj = gauss + ((size_t)b * K1 + j) * (G * G);
    float inter = 0.f, uni = 0.f;
#pragma unroll
    for (int p = lane; p < G * G; p += 64) {
        float a = gi[p], c = gj[p];
        inter += fminf(a, c);
        uni   += fmaxf(a, c);
    }
#pragma unroll
    for (int o = 32; o; o >>= 1) {
        inter += __shfl_xor(inter, o, 64);
        uni   += __shfl_xor(uni,   o, 64);
    }
    if (lane == 0) {
        float iou = inter / uni;              // both > 0
        atomicMax(&ioumax[b * K1 + j], __float_as_uint(iou));
    }
}

// ---------------- Stage 5: keep = 15 smallest iou_max (stable) + gather ----
__global__ void k_keep(const unsigned int* __restrict__ ioumax,
                       const float* __restrict__ sloc, const float* __restrict__ smask,
                       const float* __restrict__ sconf,
                       float* __restrict__ kloc, float* __restrict__ kmask,
                       float* __restrict__ kconf) {
    int b = blockIdx.x;
    int lane = threadIdx.x;  // 64 threads
    float v0 = (lane < K1)      ? __uint_as_float(ioumax[b * K1 + lane])      : INFINITY;
    float v1 = (lane + 64 < K1) ? __uint_as_float(ioumax[b * K1 + lane + 64]) : INFINITY;
    __shared__ int s_keep[K2];
    for (int k = 0; k < K2; ++k) {
        float bv; int bi;
        if (v0 <= v1) { bv = v0; bi = lane; }        // tie -> smaller index
        else          { bv = v1; bi = lane + 64; }
#pragma unroll
        for (int o = 32; o; o >>= 1) {
            float ov = __shfl_xor(bv, o, 64);
            int   oi = __shfl_xor(bi, o, 64);
            if (ov < bv || (ov == bv && oi < bi)) { bv = ov; bi = oi; }
        }
        if (bi == lane)           v0 = INFINITY;
        else if (bi == lane + 64) v1 = INFINITY;
        if (lane == 0) s_keep[k] = bi;
    }
    __syncthreads();
    for (int t = lane; t < K2 * M; t += 64) {
        int k = t >> 5, d = t & 31;
        kmask[(b * K2 + k) * M + d] = smask[(b * K1 + s_keep[k]) * M + d];
    }
    for (int t = lane; t < K2 * 4; t += 64) {
        int k = t >> 2, d = t & 3;
        kloc[(b * K2 + k) * 4 + d] = sloc[(b * K1 + s_keep[k]) * 4 + d];
    }
    if (lane < K2) kconf[b * K2 + lane] = sconf[b * K1 + s_keep[lane]];
}

// ---------------- Stage 6: final_conf at 138x138 ---------------------------
__global__ void k_fconf(const float* __restrict__ proto, const float* __restrict__ kloc,
                        const float* __restrict__ kmask, const float* __restrict__ kconf,
                        float* __restrict__ fconf) {
    int b = blockIdx.y;
    int p = blockIdx.x * 256 + threadIdx.x;
    __shared__ float s_km[K2][M];
    __shared__ float s_loc[K2][4];
    __shared__ float s_cf[K2];
    for (int t = threadIdx.x; t < K2 * M; t += 256) s_km[t >> 5][t & 31] = kmask[b * K2 * M + t];
    for (int t = threadIdx.x; t < K2 * 4; t += 256) s_loc[t >> 2][t & 3] = kloc[b * K2 * 4 + t];
    if (threadIdx.x < K2) s_cf[threadIdx.x] = kconf[b * K2 + threadIdx.x];
    __syncthreads();
    if (p >= HP * HP) return;
    int h = p / HP, w = p % HP;
    const float* pr = proto + (((size_t)b * HP + h) * HP + w) * M;
    float pv[M];
#pragma unroll
    for (int m = 0; m < M; ++m) pv[m] = pr[m];
    float ys = (h + 0.5f) / (float)HP;
    float xs = (w + 0.5f) / (float)HP;
    float sum_a = 0.f, sum_a2 = 0.f;
#pragma unroll 1
    for (int k = 0; k < K2; ++k) {
        float d = 0.f;
#pragma unroll
        for (int m = 0; m < M; ++m) d += pv[m] * s_km[k][m];
        float sig = 1.f / (1.f + expf(-d));
        float cx = s_loc[k][0], cy = s_loc[k][1];
        float sx = fabsf(s_loc[k][2]) * 0.5f + 0.001f;
        float sy = fabsf(s_loc[k][3]) * 0.5f + 0.001f;
        float dx2 = (xs - cx) * (xs - cx) / (2.f * sx * sx);
        float dy2 = (ys - cy) * (ys - cy) / (2.f * sy * sy);
        float ug = expf(-(dy2 + dx2));
        float a = sig * ug * s_cf[k];
        sum_a  += a;
        sum_a2 += a * a;
    }
    float fin = 1.f - sum_a2 / (sum_a + FEPS);
    if (!(fin == fin)) fin = 0.f;
    fconf[(size_t)b * HP * HP + p] = fin;
}

// ---------------- Stage 7: bilinear resize 138->550 fused with variance ----
__global__ void k_reduce(const float* __restrict__ fconf, const float* __restrict__ original,
                         float* __restrict__ acc) {
    int idx = blockIdx.x * 256 + threadIdx.x;
    float contrib = 0.f;
    if (idx < HO * HO) {
        int y = idx / HO, x = idx % HO;
        const float scale = (float)HP / (float)HO;
        float fy = (y + 0.5f) * scale - 0.5f;
        float fx = (x + 0.5f) * scale - 0.5f;
        float y0f = floorf(fy), x0f = floorf(fx);
        float wy = fy - y0f, wx = fx - x0f;
        int y0 = (int)y0f, x0 = (int)x0f;
        int iy0 = max(y0, 0), iy1 = min(y0 + 1, HP - 1);
        int ix0 = max(x0, 0), ix1 = min(x0 + 1, HP - 1);
        float r[B];
#pragma unroll
        for (int b = 0; b < B; ++b) {
            const float* F = fconf + (size_t)b * HP * HP;
            float v00 = F[iy0 * HP + ix0], v01 = F[iy0 * HP + ix1];
            float v10 = F[iy1 * HP + ix0], v11 = F[iy1 * HP + ix1];
            r[b] = (1.f - wy) * ((1.f - wx) * v00 + wx * v01)
                 +        wy  * ((1.f - wx) * v10 + wx * v11);
        }
        float t = r[0] + r[1] + r[2] + r[3];
        float s = 0.f;
#pragma unroll
        for (int c = 0; c < 3; ++c) {
            float o[B], wm = 0.f;
#pragma unroll
            for (int b = 0; b < B; ++b) {
                o[b] = original[(((size_t)b * 3 + c) * HO + y) * HO + x];
                wm += o[b] * r[b];
            }
#pragma unroll
            for (int b = 0; b < B; ++b) {
                float d = o[b] - wm;
                s += d * d * r[b];
            }
        }
        contrib = s / (t + FEPS);
    }
    __shared__ float red[256];
    red[threadIdx.x] = contrib;
    __syncthreads();
    for (int off = 128; off; off >>= 1) {
        if (threadIdx.x < off) red[threadIdx.x] += red[threadIdx.x + off];
        __syncthreads();
    }
    if (threadIdx.x == 0) atomicAdd(acc, red[0]);
}

__global__ void k_final(const float* __restrict__ acc, float* __restrict__ out) {
    out[0] = acc[0] / 100.f;
}

extern "C" void kernel_launch(void* const* d_in, const int* in_sizes, int n_in,
                              void* d_out, int out_size, void* d_ws, size_t ws_size,
                              hipStream_t stream) {
    (void)in_sizes; (void)n_in; (void)out_size; (void)ws_size;
    const float* original = (const float*)d_in[0];
    const float* loc      = (const float*)d_in[1];
    const float* conf     = (const float*)d_in[2];
    const float* mask     = (const float*)d_in[3];
    const float* proto    = (const float*)d_in[4];

    char* ws = (char*)d_ws;
    size_t off = 0;
    auto alloc = [&](size_t bytes) -> void* {
        void* p = ws + off;
        off += (bytes + 255) & ~(size_t)255;
        return p;
    };
    float* conf1        = (float*)alloc((size_t)B * P * sizeof(float));
    int*   order        = (int*)  alloc((size_t)B * K1 * sizeof(int));
    float* sconf        = (float*)alloc((size_t)B * K1 * sizeof(float));
    float* sloc         = (float*)alloc((size_t)B * K1 * 4 * sizeof(float));
    float* smask        = (float*)alloc((size_t)B * K1 * M * sizeof(float));
    float* gauss        = (float*)alloc((size_t)B * K1 * G * G * sizeof(float));
    unsigned int* iomax = (unsigned int*)alloc((size_t)B * K1 * sizeof(unsigned int));
    float* kloc         = (float*)alloc((size_t)B * K2 * 4 * sizeof(float));
    float* kmask        = (float*)alloc((size_t)B * K2 * M * sizeof(float));
    float* kconf        = (float*)alloc((size_t)B * K2 * sizeof(float));
    float* fconf        = (float*)alloc((size_t)B * HP * HP * sizeof(float));
    float* acc          = (float*)alloc(sizeof(float));

    hipMemsetAsync(iomax, 0, (size_t)B * K1 * sizeof(unsigned int), stream);
    hipMemsetAsync(acc, 0, sizeof(float), stream);

    // Stage 1: 76992 waves
    k_conf1<<<(B * P) / 4, 256, 0, stream>>>(conf, conf1);
    // Stage 2: one 1024-block per batch, radix-histogram select
    k_top100<<<B, 1024, 0, stream>>>(conf1, loc, mask, order, sconf, sloc, smask);
    // Stage 3
    k_gauss<<<B * K1, 256, 0, stream>>>(sloc, gauss);
    // Stage 4: one wave per (b,i,j)
    k_iou<<<(B * K1 * K1 * 64 + 255) / 256, 256, 0, stream>>>(gauss, iomax);
    // Stage 5
    k_keep<<<B, 64, 0, stream>>>(iomax, sloc, smask, sconf, kloc, kmask, kconf);
    // Stage 6
    dim3 g6((HP * HP + 255) / 256, B);
    k_fconf<<<g6, 256, 0, stream>>>(proto, kloc, kmask, kconf, fconf);
    // Stage 7
    k_reduce<<<(HO * HO + 255) / 256, 256, 0, stream>>>(fconf, original, acc);
    k_final<<<1, 1, 0, stream>>>(acc, (float*)d_out);
}

// Round 4
// 177.749 us; speedup vs baseline: 2.4262x; 1.1773x over previous
//
#include <hip/hip_runtime.h>
#include <math.h>

#define B 4
#define P 19248
#define C 81
#define M 32
#define K1 100
#define K2 15
#define G 32
#define HP 138
#define HO 550
#define FEPS 1e-6f
#define NLOC 19   // ceil(P/1024)

#define NBUCKET 8192   // bits >> 17; conf1 in (0,1) -> bucket < 8128
#define CAP 2048       // candidate cap

// iou tiling
#define TI 16          // gaussians per tile
#define NT 7           // ceil(112/16) tiles covering K1=100
#define NTP 28         // tile pairs ti<=tj
#define CH 128         // pixels per chunk
#define NCH 8          // 1024/CH
#define SP 132         // padded LDS row stride (floats): 528B/row, 16B-aligned

// ---------------- Stage 1: conf1 = softmax(conf, axis=2)[:, :, 1] ----------
__global__ void k_conf1(const float* __restrict__ conf, float* __restrict__ conf1) {
    int gid  = blockIdx.x * blockDim.x + threadIdx.x;
    int wave = gid >> 6;
    int lane = threadIdx.x & 63;
    if (wave >= B * P) return;
    const float* row = conf + (size_t)wave * C;
    float x0 = (lane < C)      ? row[lane]      : -INFINITY;
    float x1 = (lane + 64 < C) ? row[lane + 64] : -INFINITY;
    float m = fmaxf(x0, x1);
#pragma unroll
    for (int o = 32; o; o >>= 1) m = fmaxf(m, __shfl_xor(m, o, 64));
    float s = 0.f;
    if (lane < C)      s += expf(x0 - m);
    if (lane + 64 < C) s += expf(x1 - m);
#pragma unroll
    for (int o = 32; o; o >>= 1) s += __shfl_xor(s, o, 64);
    if (lane == 0) conf1[wave] = expf(row[1] - m) / s;
}

// ---------------- Stage 2: top-100 by conf1 via radix-histogram select -----
__global__ __launch_bounds__(1024) void k_top100(
    const float* __restrict__ conf1, const float* __restrict__ loc,
    const float* __restrict__ mask,  int* __restrict__ order,
    float* __restrict__ sconf, float* __restrict__ sloc,
    float* __restrict__ smask) {
    int b = blockIdx.x;
    int tid = threadIdx.x;
    const float* c1 = conf1 + (size_t)b * P;

    __shared__ unsigned int hist[NBUCKET];
    __shared__ unsigned int gsum_[1024];
    __shared__ unsigned int g2[64];
    __shared__ unsigned long long keys[CAP];
    __shared__ int s_T;
    __shared__ int s_cnt;
    __shared__ int   s_order[K1];
    __shared__ float s_conf[K1];

    for (int i = tid; i < NBUCKET; i += 1024) hist[i] = 0;
    if (tid == 0) s_cnt = 0;
    __syncthreads();

    unsigned int mybits[NLOC];
#pragma unroll
    for (int s = 0; s < NLOC; ++s) {
        int p = tid + s * 1024;
        mybits[s] = (p < P) ? __float_as_uint(c1[p]) : 0u;
        if (p < P) atomicAdd(&hist[mybits[s] >> 17], 1u);
    }
    __syncthreads();

    {
        unsigned int gs = 0;
#pragma unroll
        for (int i = 0; i < 8; ++i) gs += hist[tid * 8 + i];
        gsum_[tid] = gs;
    }
    __syncthreads();
    if (tid < 64) {
        unsigned int gs = 0;
#pragma unroll
        for (int i = 0; i < 16; ++i) gs += gsum_[tid * 16 + i];
        g2[tid] = gs;
    }
    __syncthreads();

    if (tid == 0) {
        int cum = 0;
        int S = 63;
        for (; S > 0; --S) {
            if (cum + (int)g2[S] >= K1) break;
            cum += (int)g2[S];
        }
        int gI = S * 16 + 15;
        for (; gI > S * 16; --gI) {
            if (cum + (int)gsum_[gI] >= K1) break;
            cum += (int)gsum_[gI];
        }
        int T = gI * 8 + 7;
        for (; T > gI * 8; --T) {
            cum += (int)hist[T];
            if (cum >= K1) break;
        }
        s_T = T;
    }
    __syncthreads();

    int T = s_T;
#pragma unroll
    for (int s = 0; s < NLOC; ++s) {
        int p = tid + s * 1024;
        if (p < P && (int)(mybits[s] >> 17) >= T) {
            int pos = atomicAdd(&s_cnt, 1);
            if (pos < CAP)
                keys[pos] = ((unsigned long long)mybits[s] << 32)
                          | (unsigned int)(0xFFFFFFFFu - (unsigned int)p);
        }
    }
    __syncthreads();
    int nc = min(s_cnt, CAP);

    if (tid < nc) {
        unsigned long long mk = keys[tid];
        int rank = 0;
        for (int i = 0; i < nc; ++i) rank += (keys[i] > mk);
        if (rank < K1) {
            unsigned int bits = (unsigned int)(mk >> 32);
            int idx = (int)(0xFFFFFFFFu - (unsigned int)(mk & 0xFFFFFFFFu));
            s_order[rank] = idx;
            s_conf[rank] = __uint_as_float(bits);
        }
    }
    __syncthreads();

    for (int t = tid; t < K1; t += 1024) {
        order[b * K1 + t] = s_order[t];
        sconf[b * K1 + t] = s_conf[t];
    }
    for (int t = tid; t < K1 * 4; t += 1024) {
        int k = t >> 2, d = t & 3;
        sloc[(b * K1 + k) * 4 + d] = loc[((size_t)b * P + s_order[k]) * 4 + d];
    }
    for (int t = tid; t < K1 * M; t += 1024) {
        int k = t >> 5, d = t & 31;
        smask[(b * K1 + k) * M + d] = mask[((size_t)b * P + s_order[k]) * M + d];
    }
}

// ---------------- Stage 3: 32x32 gaussians for the 100 boxes ---------------
__global__ void k_gauss(const float* __restrict__ sloc, float* __restrict__ gauss) {
    int bk = blockIdx.x;                    // b*K1 + k
    const float* l = sloc + bk * 4;
    float cx = l[0], cy = l[1];
    float sx = fabsf(l[2]) * 0.5f + 0.001f;
    float sy = fabsf(l[3]) * 0.5f + 0.001f;
    float dsx = 2.f * sx * sx;
    float dsy = 2.f * sy * sy;
    for (int p = threadIdx.x; p < G * G; p += 256) {
        int y = p >> 5, x = p & 31;
        float xs = (x + 0.5f) / (float)G;
        float ys = (y + 0.5f) / (float)G;
        float dx2 = (xs - cx) * (xs - cx) / dsx;
        float dy2 = (ys - cy) * (ys - cy) / dsy;
        gauss[(size_t)bk * (G * G) + p] = expf(-(dy2 + dx2));
    }
}

// ---------------- Stage 4a: inter/union per pair, LDS-tiled ----------------
// block = (chunk, tilepair, b); 256 threads = 16x16 pairs
// DIRECT min/max sums (no (S-D)/(S+D) identity -- that cancellation flipped
// the rank-15 selection for near-disjoint pairs in round 3).
__global__ __launch_bounds__(256) void k_iou_tile(
    const float* __restrict__ gauss, float* __restrict__ Ibuf,
    float* __restrict__ Ubuf) {
    int ch = blockIdx.x;
    int tp = blockIdx.y;
    int b  = blockIdx.z;
    int ti = 0, rem = tp;
    while (rem >= NT - ti) { rem -= NT - ti; ++ti; }
    int tj = ti + rem;

    __shared__ __align__(16) float As[TI][SP];
    __shared__ __align__(16) float Bs[TI][SP];

    int tid = threadIdx.x;
    for (int idx = tid; idx < TI * (CH / 4); idx += 256) {
        int g = idx >> 5, v = idx & 31;
        int gi = ti * TI + g;
        float4 f = make_float4(0.f, 0.f, 0.f, 0.f);
        if (gi < K1)
            f = *(const float4*)(gauss + ((size_t)(b * K1 + gi) << 10) + ch * CH + v * 4);
        *(float4*)(&As[g][v * 4]) = f;
        int gj = tj * TI + g;
        float4 h = make_float4(0.f, 0.f, 0.f, 0.f);
        if (gj < K1)
            h = *(const float4*)(gauss + ((size_t)(b * K1 + gj) << 10) + ch * CH + v * 4);
        *(float4*)(&Bs[g][v * 4]) = h;
    }
    __syncthreads();

    int li = tid >> 4, lj = tid & 15;
    int i = ti * TI + li, j = tj * TI + lj;
    if (i < j && j < K1) {
        const float4* ar = (const float4*)(&As[li][0]);
        const float4* br = (const float4*)(&Bs[lj][0]);
        float inter = 0.f, uni = 0.f;
#pragma unroll
        for (int p = 0; p < CH / 4; ++p) {
            float4 a = ar[p], c = br[p];
            inter += fminf(a.x, c.x) + fminf(a.y, c.y)
                   + fminf(a.z, c.z) + fminf(a.w, c.w);
            uni   += fmaxf(a.x, c.x) + fmaxf(a.y, c.y)
                   + fmaxf(a.z, c.z) + fmaxf(a.w, c.w);
        }
        atomicAdd(&Ibuf[(b * K1 + i) * K1 + j], inter);
        atomicAdd(&Ubuf[(b * K1 + i) * K1 + j], uni);
    }
}

// ---------------- Stage 4b: iou = I/U, atomicMax per column ----------------
__global__ void k_combine(const float* __restrict__ Ibuf, const float* __restrict__ Ubuf,
                          unsigned int* __restrict__ ioumax) {
    int gid = blockIdx.x * 256 + threadIdx.x;
    if (gid >= B * K1 * K1) return;
    int b = gid / (K1 * K1);
    int rem = gid - b * K1 * K1;
    int i = rem / K1, j = rem % K1;
    if (i >= j) return;
    float iou = Ibuf[gid] / Ubuf[gid];
    atomicMax(&ioumax[b * K1 + j], __float_as_uint(iou));
}

// ---------------- Stage 5: keep = 15 smallest iou_max (stable) + gather ----
__global__ void k_keep(const unsigned int* __restrict__ ioumax,
                       const float* __restrict__ sloc, const float* __restrict__ smask,
                       const float* __restrict__ sconf,
                       float* __restrict__ kloc, float* __restrict__ kmask,
                       float* __restrict__ kconf) {
    int b = blockIdx.x;
    int lane = threadIdx.x;  // 64 threads
    float v0 = (lane < K1)      ? __uint_as_float(ioumax[b * K1 + lane])      : INFINITY;
    float v1 = (lane + 64 < K1) ? __uint_as_float(ioumax[b * K1 + lane + 64]) : INFINITY;
    __shared__ int s_keep[K2];
    for (int k = 0; k < K2; ++k) {
        float bv; int bi;
        if (v0 <= v1) { bv = v0; bi = lane; }
        else          { bv = v1; bi = lane + 64; }
#pragma unroll
        for (int o = 32; o; o >>= 1) {
            float ov = __shfl_xor(bv, o, 64);
            int   oi = __shfl_xor(bi, o, 64);
            if (ov < bv || (ov == bv && oi < bi)) { bv = ov; bi = oi; }
        }
        if (bi == lane)           v0 = INFINITY;
        else if (bi == lane + 64) v1 = INFINITY;
        if (lane == 0) s_keep[k] = bi;
    }
    __syncthreads();
    for (int t = lane; t < K2 * M; t += 64) {
        int k = t >> 5, d = t & 31;
        kmask[(b * K2 + k) * M + d] = smask[(b * K1 + s_keep[k]) * M + d];
    }
    for (int t = lane; t < K2 * 4; t += 64) {
        int k = t >> 2, d = t & 3;
        kloc[(b * K2 + k) * 4 + d] = sloc[(b * K1 + s_keep[k]) * 4 + d];
    }
    if (lane < K2) kconf[b * K2 + lane] = sconf[b * K1 + s_keep[lane]];
}

// ---------------- Stage 6: final_conf at 138x138 (LDS-staged proto) --------
__global__ __launch_bounds__(256) void k_fconf(
    const float* __restrict__ proto, const float* __restrict__ kloc,
    const float* __restrict__ kmask, const float* __restrict__ kconf,
    float* __restrict__ fconf) {
    int b = blockIdx.y;
    int px0 = blockIdx.x * 256;
    int tid = threadIdx.x;
    __shared__ float s_pv[256][M + 1];
    __shared__ float s_km[K2][M];
    __shared__ float s_loc[K2][4];
    __shared__ float s_cf[K2];
    for (int t = tid; t < K2 * M; t += 256) s_km[t >> 5][t & 31] = kmask[b * K2 * M + t];
    for (int t = tid; t < K2 * 4; t += 256) s_loc[t >> 2][t & 3] = kloc[b * K2 * 4 + t];
    if (tid < K2) s_cf[tid] = kconf[b * K2 + tid];

    int nvalid = min(256, HP * HP - px0);
    const float4* pr4 = (const float4*)(proto + ((size_t)b * (HP * HP) + px0) * M);
    for (int idx = tid; idx < nvalid * (M / 4); idx += 256) {
        float4 f = pr4[idx];
        int q = idx >> 3, v = idx & 7;
        s_pv[q][v * 4 + 0] = f.x;
        s_pv[q][v * 4 + 1] = f.y;
        s_pv[q][v * 4 + 2] = f.z;
        s_pv[q][v * 4 + 3] = f.w;
    }
    __syncthreads();

    if (tid < nvalid) {
        int p = px0 + tid;
        int h = p / HP, w = p % HP;
        float pv[M];
#pragma unroll
        for (int m = 0; m < M; ++m) pv[m] = s_pv[tid][m];
        float ys = (h + 0.5f) / (float)HP;
        float xs = (w + 0.5f) / (float)HP;
        float sum_a = 0.f, sum_a2 = 0.f;
#pragma unroll 1
        for (int k = 0; k < K2; ++k) {
            float d = 0.f;
#pragma unroll
            for (int m = 0; m < M; ++m) d += pv[m] * s_km[k][m];
            float sig = 1.f / (1.f + expf(-d));
            float cx = s_loc[k][0], cy = s_loc[k][1];
            float sx = fabsf(s_loc[k][2]) * 0.5f + 0.001f;
            float sy = fabsf(s_loc[k][3]) * 0.5f + 0.001f;
            float dx2 = (xs - cx) * (xs - cx) / (2.f * sx * sx);
            float dy2 = (ys - cy) * (ys - cy) / (2.f * sy * sy);
            float ug = expf(-(dy2 + dx2));
            float a = sig * ug * s_cf[k];
            sum_a  += a;
            sum_a2 += a * a;
        }
        float fin = 1.f - sum_a2 / (sum_a + FEPS);
        if (!(fin == fin)) fin = 0.f;
        fconf[(size_t)b * HP * HP + p] = fin;
    }
}

// ---------------- Stage 7: bilinear resize 138->550 fused with variance ----
__global__ void k_reduce(const float* __restrict__ fconf, const float* __restrict__ original,
                         float* __restrict__ acc) {
    int idx = blockIdx.x * 256 + threadIdx.x;
    float contrib = 0.f;
    if (idx < HO * HO) {
        int y = idx / HO, x = idx % HO;
        const float scale = (float)HP / (float)HO;
        float fy = (y + 0.5f) * scale - 0.5f;
        float fx = (x + 0.5f) * scale - 0.5f;
        float y0f = floorf(fy), x0f = floorf(fx);
        float wy = fy - y0f, wx = fx - x0f;
        int y0 = (int)y0f, x0 = (int)x0f;
        int iy0 = max(y0, 0), iy1 = min(y0 + 1, HP - 1);
        int ix0 = max(x0, 0), ix1 = min(x0 + 1, HP - 1);
        float r[B];
#pragma unroll
        for (int b = 0; b < B; ++b) {
            const float* F = fconf + (size_t)b * HP * HP;
            float v00 = F[iy0 * HP + ix0], v01 = F[iy0 * HP + ix1];
            float v10 = F[iy1 * HP + ix0], v11 = F[iy1 * HP + ix1];
            r[b] = (1.f - wy) * ((1.f - wx) * v00 + wx * v01)
                 +        wy  * ((1.f - wx) * v10 + wx * v11);
        }
        float t = r[0] + r[1] + r[2] + r[3];
        float s = 0.f;
#pragma unroll
        for (int c = 0; c < 3; ++c) {
            float o[B], wm = 0.f;
#pragma unroll
            for (int b = 0; b < B; ++b) {
                o[b] = original[(((size_t)b * 3 + c) * HO + y) * HO + x];
                wm += o[b] * r[b];
            }
#pragma unroll
            for (int b = 0; b < B; ++b) {
                float d = o[b] - wm;
                s += d * d * r[b];
            }
        }
        contrib = s / (t + FEPS);
    }
    __shared__ float red[256];
    red[threadIdx.x] = contrib;
    __syncthreads();
    for (int off = 128; off; off >>= 1) {
        if (threadIdx.x < off) red[threadIdx.x] += red[threadIdx.x + off];
        __syncthreads();
    }
    if (threadIdx.x == 0) atomicAdd(acc, red[0]);
}

__global__ void k_final(const float* __restrict__ acc, float* __restrict__ out) {
    out[0] = acc[0] / 100.f;
}

extern "C" void kernel_launch(void* const* d_in, const int* in_sizes, int n_in,
                              void* d_out, int out_size, void* d_ws, size_t ws_size,
                              hipStream_t stream) {
    (void)in_sizes; (void)n_in; (void)out_size; (void)ws_size;
    const float* original = (const float*)d_in[0];
    const float* loc      = (const float*)d_in[1];
    const float* conf     = (const float*)d_in[2];
    const float* mask     = (const float*)d_in[3];
    const float* proto    = (const float*)d_in[4];

    char* ws = (char*)d_ws;
    size_t off = 0;
    auto alloc = [&](size_t bytes) -> void* {
        void* p = ws + off;
        off += (bytes + 255) & ~(size_t)255;
        return p;
    };
    float* conf1        = (float*)alloc((size_t)B * P * sizeof(float));
    int*   order        = (int*)  alloc((size_t)B * K1 * sizeof(int));
    float* sconf        = (float*)alloc((size_t)B * K1 * sizeof(float));
    float* sloc         = (float*)alloc((size_t)B * K1 * 4 * sizeof(float));
    float* smask        = (float*)alloc((size_t)B * K1 * M * sizeof(float));
    float* gauss        = (float*)alloc((size_t)B * K1 * G * G * sizeof(float));
    float* Ibuf         = (float*)alloc((size_t)B * K1 * K1 * sizeof(float));
    float* Ubuf         = (float*)alloc((size_t)B * K1 * K1 * sizeof(float));
    unsigned int* iomax = (unsigned int*)alloc((size_t)B * K1 * sizeof(unsigned int));
    float* kloc         = (float*)alloc((size_t)B * K2 * 4 * sizeof(float));
    float* kmask        = (float*)alloc((size_t)B * K2 * M * sizeof(float));
    float* kconf        = (float*)alloc((size_t)B * K2 * sizeof(float));
    float* fconf        = (float*)alloc((size_t)B * HP * HP * sizeof(float));
    float* acc          = (float*)alloc(sizeof(float));

    hipMemsetAsync(iomax, 0, (size_t)B * K1 * sizeof(unsigned int), stream);
    hipMemsetAsync(Ibuf, 0, (size_t)B * K1 * K1 * sizeof(float) * 2, stream); // Ibuf+Ubuf adjacent? no -- padded
    hipMemsetAsync(Ubuf, 0, (size_t)B * K1 * K1 * sizeof(float), stream);
    hipMemsetAsync(acc, 0, sizeof(float), stream);

    k_conf1<<<(B * P) / 4, 256, 0, stream>>>(conf, conf1);
    k_top100<<<B, 1024, 0, stream>>>(conf1, loc, mask, order, sconf, sloc, smask);
    k_gauss<<<B * K1, 256, 0, stream>>>(sloc, gauss);
    dim3 g4(NCH, NTP, B);
    k_iou_tile<<<g4, 256, 0, stream>>>(gauss, Ibuf, Ubuf);
    k_combine<<<(B * K1 * K1 + 255) / 256, 256, 0, stream>>>(Ibuf, Ubuf, iomax);
    k_keep<<<B, 64, 0, stream>>>(iomax, sloc, smask, sconf, kloc, kmask, kconf);
    dim3 g6((HP * HP + 255) / 256, B);
    k_fconf<<<g6, 256, 0, stream>>>(proto, kloc, kmask, kconf, fconf);
    k_reduce<<<(HO * HO + 255) / 256, 256, 0, stream>>>(fconf, original, acc);
    k_final<<<1, 1, 0, stream>>>(acc, (float*)d_out);
}